// Round 6
// baseline (66.621 us; speedup 1.0000x reference)
//
#include <hip/hip_runtime.h>
#include <cstddef>

#define Bn 16
#define Dn 512
#define Tn 2048
#define Ln 512
#define NLT 64      // l-tiles per b (Ln/8)
#define AZT 16      // t-chunk in fused kernel

// ---------------- K1: score[b,t] = exp(x[b,:,t].w) * mask ----------------
__global__ __launch_bounds__(256) void score_kernel(const float* __restrict__ x,
                                                    const float* __restrict__ w,
                                                    const int* __restrict__ xlen,
                                                    float* __restrict__ score) {
    int blk = blockIdx.x;
    int b   = blk >> 5;
    int tc  = blk & 31;
    int tid = threadIdx.x;
    int xl  = xlen[b];
    int t0c = tc * 64;
    if (t0c >= xl) {
        if (tid < 16)
            *(float4*)&score[b * Tn + t0c + tid * 4] = make_float4(0.f, 0.f, 0.f, 0.f);
        return;
    }
    int tq  = tid & 15;
    int dg  = tid >> 4;
    int t0  = t0c + tq * 4;
    const float* xb = x + (size_t)b * Dn * Tn + t0;
    float4 acc = make_float4(0.f, 0.f, 0.f, 0.f);
    int dbase = dg * 32;
#pragma unroll 8
    for (int i = 0; i < 32; ++i) {
        int d = dbase + i;
        float4 v = *(const float4*)&xb[(size_t)d * Tn];
        float wd = w[d];
        acc.x = fmaf(v.x, wd, acc.x);
        acc.y = fmaf(v.y, wd, acc.y);
        acc.z = fmaf(v.z, wd, acc.z);
        acc.w = fmaf(v.w, wd, acc.w);
    }
    __shared__ float4 red[16][16];
    red[dg][tq] = acc;
    __syncthreads();
    if (tid < 16) {
        float4 s = red[0][tid];
#pragma unroll
        for (int g = 1; g < 16; ++g) {
            float4 r = red[g][tid];
            s.x += r.x; s.y += r.y; s.z += r.z; s.w += r.w;
        }
        int t = t0c + tid * 4;
        float4 o;
        o.x = (t + 0 < xl) ? __expf(s.x) : 0.f;
        o.y = (t + 1 < xl) ? __expf(s.y) : 0.f;
        o.z = (t + 2 < xl) ? __expf(s.z) : 0.f;
        o.w = (t + 3 < xl) ? __expf(s.w) : 0.f;
        *(float4*)&score[b * Tn + t] = o;
    }
}

// -------- K2: per-b scan -> norm, loss partial, z_mask, z_len, windows ---
// Window tables: for each l-tile lt (8 l's), margin 1.5:
//   wlo[lt] = first t with norm[t] >= 8*lt - 1.5   (default xl)
//   whi[lt] = first t with norm[t] >  8*lt + 8.5   (default xl)
// norm is monotone non-decreasing -> each threshold crossed at exactly one t.
__global__ __launch_bounds__(256) void scan_kernel(const float* __restrict__ score,
                                                   const int* __restrict__ xlen,
                                                   float* __restrict__ norm,
                                                   float* __restrict__ loss_part,
                                                   float* __restrict__ zmask_out,
                                                   float* __restrict__ zlen_out,
                                                   int* __restrict__ wlo,
                                                   int* __restrict__ whi) {
    int b = blockIdx.x, tid = threadIdx.x;
    int xl = xlen[b];
    int zl = (xl + 3) >> 2;
    const float* sc = score + b * Tn;

    __shared__ float sNorm[Tn];   // 8 KB

    float v[8]; float s = 0.f;
#pragma unroll
    for (int k = 0; k < 8; ++k) { v[k] = sc[tid * 8 + k]; s += v[k]; }

    float ps = s;
#pragma unroll
    for (int off = 1; off < 64; off <<= 1) {
        float n = __shfl_up(ps, off, 64);
        if ((tid & 63) >= off) ps += n;
    }
    __shared__ float wsum[4];
    if ((tid & 63) == 63) wsum[tid >> 6] = ps;
    __syncthreads();
    float base = 0.f;
#pragma unroll
    for (int wv = 0; wv < 4; ++wv) if (wv < (tid >> 6)) base += wsum[wv];
    float total = wsum[0] + wsum[1] + wsum[2] + wsum[3];
    float cum0  = sc[0];
    float scale = (float)(zl - 1) / (total - cum0);

    float run = base + ps - s;
    float nv[8];
#pragma unroll
    for (int k = 0; k < 8; ++k) {
        run += v[k];
        float x = (run - cum0) * scale;
        nv[k] = x;
        norm[b * Tn + tid * 8 + k] = x;
        sNorm[tid * 8 + k] = x;
    }

    float ls = 0.f;
#pragma unroll
    for (int k = 0; k < 8; ++k) {
        int t = tid * 8 + k;
        if (t >= 1 && t < xl) {
            float diff = v[k] * scale;
            ls += fmaxf(diff - 1.0f, 0.f);
        }
    }
#pragma unroll
    for (int off = 32; off; off >>= 1) ls += __shfl_down(ls, off, 64);
    __shared__ float lw[4];
    if ((tid & 63) == 0) lw[tid >> 6] = ls;

    for (int l = tid; l < Ln; l += 256)
        zmask_out[b * Ln + l] = (l * 4 < xl) ? 1.f : 0.f;
    if (tid == 0) zlen_out[b] = (float)zl;

    // window-table defaults
    for (int i = tid; i < NLT; i += 256) {
        wlo[b * NLT + i] = xl;
        whi[b * NLT + i] = xl;
    }
    __syncthreads();
    if (tid == 0) loss_part[b] = (lw[0] + lw[1] + lw[2] + lw[3]) / (float)(xl - 1);

    // crossing detection
#pragma unroll
    for (int k = 0; k < 8; ++k) {
        int t = tid * 8 + k;
        float vv = nv[k];
        float p  = (t == 0) ? -1e9f : sNorm[t - 1];
        // wlo: lt with  p < 8lt-1.5 <= vv
        int lsr = (int)floorf((p + 1.5f) * 0.125f) + 1; if (lsr < 0) lsr = 0;
        int ler = (int)floorf((vv + 1.5f) * 0.125f);    if (ler > NLT - 1) ler = NLT - 1;
        for (int lt = lsr; lt <= ler; ++lt) wlo[b * NLT + lt] = t;
        // whi: lt with  p <= 8lt+8.5 < vv
        int hs = (int)ceilf((p - 8.5f) * 0.125f);       if (hs < 0) hs = 0;
        int he = (int)ceilf((vv - 8.5f) * 0.125f) - 1;  if (he > NLT - 1) he = NLT - 1;
        for (int lt = hs; lt <= he; ++lt) whi[b * NLT + lt] = t;
    }
}

// -------- K3 (fused): alignment rows + z for one (b, l-tile) -------------
// 256 thr / block, grid Bn*NLT = 1024 (XCD-swizzled). Lane owns d = tid and
// tid+256 over all 8 l. A-tile staged in 1KB double-buffered LDS; x loaded
// float4-along-t straight to registers. One barrier per 16-t chunk.
__global__ __launch_bounds__(256) void alignz_kernel(const float* __restrict__ x,
                                                     const float* __restrict__ norm,
                                                     const int* __restrict__ xlen,
                                                     const int* __restrict__ wlo,
                                                     const int* __restrict__ whi,
                                                     const float* __restrict__ loss_part,
                                                     float* __restrict__ align,
                                                     float* __restrict__ z,
                                                     float* __restrict__ out_loss) {
    int tid = threadIdx.x;
    if (blockIdx.x == 0 && tid == 0) {
        float s = 0.f;
        for (int i = 0; i < Bn; ++i) s += loss_part[i];
        out_loss[0] = s / (float)Bn;
    }
    int wg  = blockIdx.x;
    int swz = (wg & 7) * 128 + (wg >> 3);   // bijective: 1024 % 8 == 0
    int b   = swz >> 6;
    int lt  = swz & 63;
    int l0  = lt * 8;
    int xl  = xlen[b];
    int zl  = (xl + 3) >> 2;

    float* arow = align + (size_t)(b * Ln + l0) * Tn;
    const float4 z4 = make_float4(0.f, 0.f, 0.f, 0.f);
    size_t zr0 = (size_t)(b * Dn + tid) * Ln + l0;
    size_t zr1 = (size_t)(b * Dn + 256 + tid) * Ln + l0;

    if (l0 >= zl) {                          // fully masked l-tile
#pragma unroll
        for (int r = 0; r < 8; ++r)
            for (int q = tid; q < Tn / 4; q += 256)
                *(float4*)&arow[(size_t)r * Tn + 4 * q] = z4;
        *(float4*)&z[zr0] = z4; *(float4*)&z[zr0 + 4] = z4;
        *(float4*)&z[zr1] = z4; *(float4*)&z[zr1 + 4] = z4;
        return;
    }

    int tlo = wlo[b * NLT + lt];
    int thi = whi[b * NLT + lt];
    if (thi > xl) thi = xl;
    int tA   = tlo & ~3;
    int nch  = (thi > tA) ? ((thi - tA + AZT - 1) / AZT) : 0;
    int tEnd = tA + nch * AZT; if (tEnd > Tn) tEnd = Tn;

    // zero-fill align outside [tA, tEnd)
    int preQ = tA >> 2, postQ = tEnd >> 2;
#pragma unroll
    for (int r = 0; r < 8; ++r) {
        for (int q = tid; q < preQ; q += 256)
            *(float4*)&arow[(size_t)r * Tn + 4 * q] = z4;
        for (int q = postQ + tid; q < Tn / 4; q += 256)
            *(float4*)&arow[(size_t)r * Tn + 4 * q] = z4;
    }

    if (nch == 0) {                          // degenerate (shouldn't happen)
        *(float4*)&z[zr0] = z4; *(float4*)&z[zr0 + 4] = z4;
        *(float4*)&z[zr1] = z4; *(float4*)&z[zr1 + 4] = z4;
        return;
    }

    // ---- phase 1: online max/sum per l-row over [tlo, thi) ----
    const float* nb = norm + b * Tn;
    int row = tid >> 5, ln32 = tid & 31;
    float lrow = (float)(l0 + row);
    float m = -1e30f, ssum = 0.f;
    for (int t = tlo + ln32; t < thi; t += 32) {
        float df = lrow - nb[t];
        float dd = -5.f * df * df;
        float mn = fmaxf(m, dd);
        ssum = ssum * __expf(m - mn) + __expf(dd - mn);
        m = mn;
    }
#pragma unroll
    for (int off = 16; off; off >>= 1) {
        float m2 = __shfl_xor(m, off, 32);
        float s2 = __shfl_xor(ssum, off, 32);
        float mn = fmaxf(m, m2);
        ssum = ssum * __expf(m - mn) + s2 * __expf(m2 - mn);
        m = mn;
    }
    __shared__ float sM[8], sI[8];
    if (ln32 == 0) { sM[row] = m; sI[row] = (ssum > 0.f) ? 1.f / ssum : 0.f; }

    __shared__ float sA[2][AZT][8];
    __syncthreads();                          // sM/sI ready

    const float* xr0 = x + (size_t)(b * Dn + tid) * Tn;
    const float* xr1 = xr0 + (size_t)256 * Tn;
    float4 rxA[2][4], rxB[2][4];
    float acc0[8] = {}, acc1[8] = {};

#define COMPA(CH, BUF)                                                         \
    if (tid < 128) {                                                           \
        int t = tA + (CH) * AZT + (tid & 15);                                  \
        int l = tid >> 4;                                                      \
        float a = 0.f;                                                         \
        if (t < thi && (l0 + l) < zl) {                                        \
            float df = (float)(l0 + l) - nb[t];                                \
            float dd = -5.f * df * df;                                         \
            a = __expf(dd - sM[l]) * sI[l];                                    \
        }                                                                      \
        sA[BUF][tid & 15][l] = a;                                              \
        if (t < Tn) arow[(size_t)l * Tn + t] = a;                              \
    }
#define XLOAD(RX, CH)                                                          \
    {                                                                          \
        int t0 = tA + (CH) * AZT;                                              \
        _Pragma("unroll")                                                      \
        for (int j = 0; j < 4; ++j) {                                          \
            int tj = t0 + 4 * j; if (tj > Tn - 4) tj = Tn - 4;                 \
            RX[0][j] = *(const float4*)&xr0[tj];                               \
            RX[1][j] = *(const float4*)&xr1[tj];                               \
        }                                                                      \
    }
#define COMPUTE(RX, BUF)                                                       \
    {                                                                          \
        _Pragma("unroll")                                                      \
        for (int t = 0; t < AZT; ++t) {                                        \
            float4 a0 = *(const float4*)&sA[BUF][t][0];                        \
            float4 a1 = *(const float4*)&sA[BUF][t][4];                        \
            float x0 = ((const float*)&RX[0][t >> 2])[t & 3];                  \
            float x1 = ((const float*)&RX[1][t >> 2])[t & 3];                  \
            float aw[8] = {a0.x, a0.y, a0.z, a0.w, a1.x, a1.y, a1.z, a1.w};    \
            _Pragma("unroll")                                                  \
            for (int j = 0; j < 8; ++j) {                                      \
                acc0[j] = fmaf(x0, aw[j], acc0[j]);                            \
                acc1[j] = fmaf(x1, aw[j], acc1[j]);                            \
            }                                                                  \
        }                                                                      \
    }

    COMPA(0, 0);
    XLOAD(rxA, 0);
    for (int it = 0; it < nch; it += 2) {
        __syncthreads();                      // current buf ready
        if (it + 1 < nch) { XLOAD(rxB, it + 1); COMPA(it + 1, 1); }
        COMPUTE(rxA, 0);
        __syncthreads();                      // buf0 consumed
        if (it + 2 < nch) { XLOAD(rxA, it + 2); COMPA(it + 2, 0); }
        if (it + 1 < nch) COMPUTE(rxB, 1);
    }

    *(float4*)&z[zr0]     = make_float4(acc0[0], acc0[1], acc0[2], acc0[3]);
    *(float4*)&z[zr0 + 4] = make_float4(acc0[4], acc0[5], acc0[6], acc0[7]);
    *(float4*)&z[zr1]     = make_float4(acc1[0], acc1[1], acc1[2], acc1[3]);
    *(float4*)&z[zr1 + 4] = make_float4(acc1[4], acc1[5], acc1[6], acc1[7]);
#undef COMPA
#undef XLOAD
#undef COMPUTE
}

extern "C" void kernel_launch(void* const* d_in, const int* in_sizes, int n_in,
                              void* d_out, int out_size, void* d_ws, size_t ws_size,
                              hipStream_t stream) {
    const float* x    = (const float*)d_in[0];
    const float* w    = (const float*)d_in[1];
    const int*   xlen = (const int*)d_in[3];
    float* out = (float*)d_out;

    const size_t OFF_Z     = 0;
    const size_t OFF_ZMASK = (size_t)Bn * Dn * Ln;
    const size_t OFF_ZLEN  = OFF_ZMASK + (size_t)Bn * Ln;
    const size_t OFF_ALIGN = OFF_ZLEN + Bn;
    const size_t OFF_LOSS  = OFF_ALIGN + (size_t)Bn * Ln * Tn;

    float* score     = (float*)d_ws;
    float* norm      = score + (size_t)Bn * Tn;
    float* loss_part = norm + (size_t)Bn * Tn;
    int*   wlo       = (int*)(loss_part + Bn);
    int*   whi       = wlo + Bn * NLT;

    score_kernel<<<Bn * 32, 256, 0, stream>>>(x, w, xlen, score);
    scan_kernel<<<Bn, 256, 0, stream>>>(score, xlen, norm, loss_part,
                                        out + OFF_ZMASK, out + OFF_ZLEN, wlo, whi);
    alignz_kernel<<<Bn * NLT, 256, 0, stream>>>(x, norm, xlen, wlo, whi, loss_part,
                                                out + OFF_ALIGN, out + OFF_Z,
                                                out + OFF_LOSS);
}